// Round 9
// baseline (293.488 us; speedup 1.0000x reference)
//
#include <hip/hip_runtime.h>
#include <hip/hip_bf16.h>

#define RD 64
#define UD 64
#define VD 64
#define HD 128
#define XD 64
#define NB 8
#define SITES 1024

typedef float f32x4 __attribute__((ext_vector_type(4)));
typedef __bf16 bf16x4 __attribute__((ext_vector_type(4)));
typedef __bf16 bf16x8 __attribute__((ext_vector_type(8)));
typedef unsigned int u32x4 __attribute__((ext_vector_type(4)));
typedef unsigned short u16;
typedef unsigned short u16x4 __attribute__((ext_vector_type(4)));

// ---------------- kprep: all three input transforms in one launch ----------------
// b < 256   : w2 [x][r][h] fp32 -> w2p bf16 [r][x][pos], h-PERMUTED for GEMM2:
//             pos = k2*32 + q*8 + jhi*4 + jl  <->  h = k2*32 + jhi*16 + q*4 + jl
//             (bakes the GEMM1-C-layout k-order into the weights so k_main needs
//              no cross-lane shuffle; h-permutation of a contraction is free)
// b < 384   : r  [n][s][r] fp32 -> rt fp32 [n][r][s]
// else      : u  [n][r][u][v] fp32 -> ut fp32 [r][u][v][n]   (2048 blocks)
__global__ void kprep(const float* __restrict__ w2, u16* __restrict__ w2p,
                      const float* __restrict__ r, float* __restrict__ rt,
                      const float* __restrict__ u, float* __restrict__ ut) {
  __shared__ float tl[64][68];
  int b = blockIdx.x;
  int t = threadIdx.x;
  if (b < 256) {
    int rr = b >> 2, qq = b & 3;
    for (int i = 0; i < 8; ++i) {
      int idx = qq * 2048 + i * 256 + t;   // (x,pos)
      int x = idx >> 7, pos = idx & 127;
      int k2 = pos >> 5, qd = (pos >> 3) & 3, jhi = (pos >> 2) & 1, jl = pos & 3;
      int hsrc = k2 * 32 + jhi * 16 + qd * 4 + jl;
      float val = w2[((size_t)x * RD + rr) * HD + hsrc];
      __hip_bfloat16 hv = __float2bfloat16(val);
      w2p[((size_t)rr * XD + x) * HD + pos] = *(u16*)&hv;
    }
  } else if (b < 384) {
    int bb = b - 256;
    int n = bb >> 4, sb = (bb & 15) * 64;
    for (int i = 0; i < 4; ++i) {
      int flat = i * 256 + t;
      int s = flat >> 4, ch = flat & 15;
      f32x4 d = *(const f32x4*)(r + ((size_t)(n * SITES + sb + s) * RD + ch * 4));
      *(f32x4*)&tl[s][ch * 4] = d;
    }
    __syncthreads();
    for (int i = 0; i < 4; ++i) {
      int flat = i * 256 + t;
      int rr = flat >> 4, ch = flat & 15;
      f32x4 o;
      o.x = tl[ch * 4 + 0][rr];
      o.y = tl[ch * 4 + 1][rr];
      o.z = tl[ch * 4 + 2][rr];
      o.w = tl[ch * 4 + 3][rr];
      *(f32x4*)(rt + ((size_t)(n * RD + rr) * SITES + sb + ch * 4)) = o;
    }
  } else {
    int f = (b - 384) * 256 + t;        // 524288 f32x4 units of ut
    int nh = f & 1, v = (f >> 1) & 63, uu = (f >> 7) & 63, rr = f >> 13;
    f32x4 o;
#pragma unroll
    for (int k = 0; k < 4; ++k)
      o[k] = u[(((size_t)(nh * 4 + k) * RD + rr) * UD + uu) * VD + v];
    *(f32x4*)(ut + (size_t)f * 4) = o;
  }
}

// ---------------- k_a: partial a over u-halves (R6 known-good, unchanged) -------
__global__ __launch_bounds__(256, 4) void k_a(const float* __restrict__ w1,
                                              const float* __restrict__ ut,
                                              float* __restrict__ part) {
  __shared__ float tile[32][34];      // h-local x v-local (+2 pad)
  int b = blockIdx.x;                 // 1024 = rr(64) x uh(2) x vh(2) x hb(4)
  int rr = b >> 4, uh = (b >> 3) & 1, vh = (b >> 2) & 1, hb = b & 3;
  int t = threadIdx.x;
  int vl = t >> 3, hs = t & 7;        // v-local (32), h-strip (4 h each)
  int v = vh * 32 + vl;
  int h0 = hb * 32 + hs * 4;
  const float* w1p = w1 + ((size_t)((rr * UD) + uh * 32) * VD + v) * HD + h0;
  const float* up  = ut + ((size_t)((rr * UD) + uh * 32) * VD + v) * NB;

  float acc[8][4];
#pragma unroll
  for (int n = 0; n < 8; ++n)
#pragma unroll
    for (int j = 0; j < 4; ++j) acc[n][j] = 0.f;

#pragma unroll 4
  for (int uu = 0; uu < 32; ++uu) {
    f32x4 wv = *(const f32x4*)(w1p + (size_t)uu * (VD * HD));
    f32x4 a0 = *(const f32x4*)(up + (size_t)uu * (VD * NB));
    f32x4 a1 = *(const f32x4*)(up + (size_t)uu * (VD * NB) + 4);
    float un[8];
    un[0] = a0.x; un[1] = a0.y; un[2] = a0.z; un[3] = a0.w;
    un[4] = a1.x; un[5] = a1.y; un[6] = a1.z; un[7] = a1.w;
#pragma unroll
    for (int n = 0; n < 8; ++n)
#pragma unroll
      for (int j = 0; j < 4; ++j) acc[n][j] += un[n] * wv[j];
  }

  // epilogue: LDS transpose per n -> f32x4 stores along v (full 128 B runs)
  int hl = t >> 3, vs = t & 7;
  float* pb = part + (size_t)uh * (NB * RD * HD * VD);
  for (int n = 0; n < 8; ++n) {
    __syncthreads();
#pragma unroll
    for (int j = 0; j < 4; ++j) tile[hs * 4 + j][vl] = acc[n][j];
    __syncthreads();
    f32x4 blk = *(const f32x4*)&tile[hl][vs * 4];
    *(f32x4*)(pb + ((size_t)(n * RD + rr) * HD + hb * 32 + hl) * VD + vh * 32 + vs * 4) = blk;
  }
}

// ---------------- k_a_red: at[n][r][h][v] bf16 = part[0] + part[1] (R6) ---------
__global__ __launch_bounds__(256) void k_a_red(const float* __restrict__ part,
                                               u16* __restrict__ at) {
  int i0 = blockIdx.x * 256 + threadIdx.x;   // 262144 threads, 4 f32x4 each
  const float* p1 = part + (size_t)NB * RD * HD * VD;
#pragma unroll
  for (int k = 0; k < 4; ++k) {
    size_t i = ((size_t)i0 + (size_t)k * 262144) * 4;
    f32x4 a = *(const f32x4*)(part + i);
    f32x4 c = *(const f32x4*)(p1 + i);
    u16x4 o;
#pragma unroll
    for (int j = 0; j < 4; ++j) {
      __hip_bfloat16 hv = __float2bfloat16(a[j] + c[j]);
      o[j] = *(u16*)&hv;
    }
    *(u16x4*)(at + i) = o;
  }
}

// ---------------- k_main: barrier-free fused GEMM1 + relu*r + GEMM2 -------------
// One wave per block owns an s-32 strip and all 128 h of GEMM1 (cc[8][2]); the
// GEMM1-C -> GEMM2-A layout transform is the IDENTITY because the h-order of
// GEMM2's K dimension is permuted to match (inverse baked into w2p by kprep).
// R8 lesson: ds_bpermute tile-select pulled source-lane-evaluated registers ->
// wrong tile for half the dest lanes.  This version has NO cross-lane ops at
// all: A-frag = register concat {pw0[2k2], pw1[2k2], pw0[2k2+1], pw1[2k2+1]}.
// No LDS, no __syncthreads.  2048 blocks x 64 thr = 8 blocks/CU = 8 waves/CU.
__global__ __launch_bounds__(64, 2) void k_main(const float* __restrict__ vin,
                                                const u16* __restrict__ at,
                                                const u16* __restrict__ w2p,
                                                const float* __restrict__ rt,
                                                float* __restrict__ pbuf) {
  int b = blockIdx.x;                 // 2048 = n(8) x rc(8) x stile(32), stile inner
  int stile = b & 31, rc = (b >> 5) & 7, n = b >> 8;
  int t = threadIdx.x;                // one wave
  int q = t >> 4, c = t & 15;

  // V-frags (B-op of GEMM1), fixed for the whole rr loop
  bf16x8 vf[2][2];
#pragma unroll
  for (int nt = 0; nt < 2; ++nt)
#pragma unroll
    for (int ks = 0; ks < 2; ++ks) {
      const float* vp = vin + ((size_t)(n * SITES + stile * 32 + nt * 16 + c) * VD +
                               ks * 32 + q * 8);
      f32x4 a0 = *(const f32x4*)vp;
      f32x4 a1 = *(const f32x4*)(vp + 4);
      bf16x8 f;
      f[0] = (__bf16)a0.x; f[1] = (__bf16)a0.y; f[2] = (__bf16)a0.z; f[3] = (__bf16)a0.w;
      f[4] = (__bf16)a1.x; f[5] = (__bf16)a1.y; f[6] = (__bf16)a1.z; f[7] = (__bf16)a1.w;
      vf[nt][ks] = f;
    }

  f32x4 o[2][4];
#pragma unroll
  for (int i = 0; i < 2; ++i)
#pragma unroll
    for (int j = 0; j < 4; ++j) o[i][j] = (f32x4)0.f;

  for (int rr = rc * 8; rr < rc * 8 + 8; ++rr) {
    const u16* abase = at + (size_t)(n * RD + rr) * 8192;   // [h][v] plain

    // A-frags of GEMM1: all 8 h-tiles (16 B/lane each, L2/L3-hot)
    bf16x8 af[8][2];
#pragma unroll
    for (int mt = 0; mt < 8; ++mt)
#pragma unroll
      for (int ks = 0; ks < 2; ++ks)
        af[mt][ks] = *(const bf16x8*)(abase + (size_t)(mt * 16 + c) * VD +
                                      (ks * 4 + q) * 8);
    float rsc[2];
#pragma unroll
    for (int nt = 0; nt < 2; ++nt)
      rsc[nt] = rt[(size_t)(n * RD + rr) * SITES + stile * 32 + nt * 16 + c];

    // GEMM1: P^T = A_r^T (m=h 128) x V^T (n=s 32), K=v=64
    f32x4 cc[8][2];
#pragma unroll
    for (int mt = 0; mt < 8; ++mt)
#pragma unroll
      for (int nt = 0; nt < 2; ++nt) cc[mt][nt] = (f32x4)0.f;
#pragma unroll
    for (int ks = 0; ks < 2; ++ks)
#pragma unroll
      for (int mt = 0; mt < 8; ++mt)
#pragma unroll
        for (int nt = 0; nt < 2; ++nt)
          cc[mt][nt] = __builtin_amdgcn_mfma_f32_16x16x32_bf16(af[mt][ks], vf[nt][ks],
                                                               cc[mt][nt], 0, 0, 0);

    // relu * r, pack each tile's 4 lane-values into two bf16x2 words
    // lane (q,c) tile mt regs jj hold P[s = nt*16+c][h = mt*16 + q*4 + jj]
    unsigned int pw0[8][2], pw1[8][2];
#pragma unroll
    for (int mt = 0; mt < 8; ++mt)
#pragma unroll
      for (int nt = 0; nt < 2; ++nt) {
        unsigned int w_[4];
#pragma unroll
        for (int jj = 0; jj < 4; ++jj) {
          float x = cc[mt][nt][jj];
          x = x > 0.f ? x : 0.f;
          __hip_bfloat16 hv = __float2bfloat16(x * rsc[nt]);
          w_[jj] = *(u16*)&hv;
        }
        pw0[mt][nt] = w_[0] | (w_[1] << 16);
        pw1[mt][nt] = w_[2] | (w_[3] << 16);
      }

    // GEMM2: O[s,x] += P x W2r^T, K=h=128 in permuted h-order (w2p matches).
    // A-frag for k2 = identity register concat; B-frag contiguous from w2p.
#pragma unroll
    for (int k2 = 0; k2 < 4; ++k2) {
      u32x4 wk[4];
#pragma unroll
      for (int xt = 0; xt < 4; ++xt)
        wk[xt] = *(const u32x4*)((const char*)w2p +
                  (((size_t)(rr * XD + xt * 16 + c)) * HD + k2 * 32 + q * 8) * 2);
#pragma unroll
      for (int nt = 0; nt < 2; ++nt) {
        u32x4 fa;
        fa.x = pw0[2 * k2][nt];
        fa.y = pw1[2 * k2][nt];
        fa.z = pw0[2 * k2 + 1][nt];
        fa.w = pw1[2 * k2 + 1][nt];
        bf16x8 pf = __builtin_bit_cast(bf16x8, fa);
#pragma unroll
        for (int xt = 0; xt < 4; ++xt)
          o[nt][xt] = __builtin_amdgcn_mfma_f32_16x16x32_bf16(
              pf, __builtin_bit_cast(bf16x8, wk[xt]), o[nt][xt], 0, 0, 0);
      }
    }
  }
  // epilogue: plain vector stores to pbuf[rc][n][stile][x][s32]
#pragma unroll
  for (int nt = 0; nt < 2; ++nt)
#pragma unroll
    for (int xt = 0; xt < 4; ++xt) {
      int sl = nt * 16 + q * 4;
      int x = xt * 16 + c;
      size_t off = ((((size_t)rc * NB + n) * 32 + stile) * XD + x) * 32 + sl;
      *(f32x4*)(pbuf + off) = o[nt][xt];
    }
}

// ---------------- k_reduce: out[n][s][x] = sum_rc pbuf[rc][n][stile][x][s32] ----
__global__ __launch_bounds__(256) void k_reduce(const float* __restrict__ pbuf,
                                                float* __restrict__ out) {
  __shared__ float tile[64][33];
  int b = blockIdx.x;                 // 256 = n(8) x stile(32)
  int n = b >> 5, stile = b & 31;
  int t = threadIdx.x;
#pragma unroll
  for (int p = 0; p < 2; ++p) {
    int flat = p * 256 + t;           // 512 f32x4 units over (x, s)
    int x = flat >> 3, sq = flat & 7;
    f32x4 sum = (f32x4)0.f;
#pragma unroll
    for (int rcc = 0; rcc < 8; ++rcc) {
      size_t off = ((((size_t)rcc * NB + n) * 32 + stile) * XD + x) * 32 + sq * 4;
      f32x4 d = *(const f32x4*)(pbuf + off);
      sum.x += d.x; sum.y += d.y; sum.z += d.z; sum.w += d.w;
    }
#pragma unroll
    for (int k = 0; k < 4; ++k) tile[x][sq * 4 + k] = sum[k];
  }
  __syncthreads();
#pragma unroll
  for (int p = 0; p < 2; ++p) {
    int flat = p * 256 + t;
    int sl = flat >> 4, xq = flat & 15;
    f32x4 o;
#pragma unroll
    for (int j = 0; j < 4; ++j) o[j] = tile[xq * 4 + j][sl];
    *(f32x4*)(out + ((size_t)(n * SITES + stile * 32 + sl) * XD + xq * 4)) = o;
  }
}

extern "C" void kernel_launch(void* const* d_in, const int* in_sizes, int n_in,
                              void* d_out, int out_size, void* d_ws, size_t ws_size,
                              hipStream_t stream) {
  const float* r  = (const float*)d_in[0];
  const float* u  = (const float*)d_in[1];
  const float* v  = (const float*)d_in[2];
  const float* w1 = (const float*)d_in[3];
  const float* w2 = (const float*)d_in[4];
  float* out = (float*)d_out;
  char* ws = (char*)d_ws;
  u16* at     = (u16*)(ws);                         // 8 MB  bf16 a, [n][r][h][v]
  u16* w2p    = (u16*)(ws + ((size_t)8 << 20));     // 1 MB  bf16 w2 [r][x][pos] h-permuted
  float* rt   = (float*)(ws + ((size_t)9 << 20));   // 2 MB  fp32 r [n][r][s]
  float* ut   = (float*)(ws + ((size_t)11 << 20));  // 8 MB  fp32 u [r][u][v][n]
  float* part = (float*)(ws + ((size_t)19 << 20));  // 32 MB fp32 a-partials [uh][n][r][h][v]
  float* pbuf = (float*)(ws + ((size_t)51 << 20));  // 16 MB fp32 out-partials [rc][n][stile][x][s32]

  hipLaunchKernelGGL(kprep, dim3(2432), dim3(256), 0, stream, w2, w2p, r, rt, u, ut);
  hipLaunchKernelGGL(k_a, dim3(1024), dim3(256), 0, stream, w1, ut, part);
  hipLaunchKernelGGL(k_a_red, dim3(1024), dim3(256), 0, stream, part, at);
  hipLaunchKernelGGL(k_main, dim3(2048), dim3(64), 0, stream, v, at, w2p, rt, pbuf);
  hipLaunchKernelGGL(k_reduce, dim3(256), dim3(256), 0, stream, pbuf, out);
}

// Round 10
// 269.082 us; speedup vs baseline: 1.0907x; 1.0907x over previous
//
#include <hip/hip_runtime.h>
#include <hip/hip_bf16.h>

#define RD 64
#define UD 64
#define VD 64
#define HD 128
#define XD 64
#define NB 8
#define SITES 1024

typedef float f32x4 __attribute__((ext_vector_type(4)));
typedef __bf16 bf16x4 __attribute__((ext_vector_type(4)));
typedef __bf16 bf16x8 __attribute__((ext_vector_type(8)));
typedef unsigned int u32x4 __attribute__((ext_vector_type(4)));
typedef unsigned short u16;
typedef unsigned short u16x4 __attribute__((ext_vector_type(4)));

// Raw workgroup barrier WITHOUT the vmcnt(0) drain __syncthreads carries.
// 0xC07F = lgkmcnt(0), vmcnt=63 (open), expcnt=7 (open) on gfx9-lineage.
// LDS producer->consumer only needs lgkmcnt(0) before barrier arrival; global
// prefetches stay in flight across the barrier (AITER-style).
__device__ __forceinline__ void lds_barrier() {
  __builtin_amdgcn_s_waitcnt(0xC07F);
  __builtin_amdgcn_s_barrier();
}

// ---------------- kprep: all three input transforms in one launch ----------------
// b < 256   : w2 [x][r][h] fp32 -> w2t bf16 [r][x][h]
// b < 384   : r  [n][s][r] fp32 -> rt fp32 [n][r][s]
// else      : u  [n][r][u][v] fp32 -> ut fp32 [r][u][v][n]   (2048 blocks)
__global__ void kprep(const float* __restrict__ w2, u16* __restrict__ w2t,
                      const float* __restrict__ r, float* __restrict__ rt,
                      const float* __restrict__ u, float* __restrict__ ut) {
  __shared__ float tl[64][68];
  int b = blockIdx.x;
  int t = threadIdx.x;
  if (b < 256) {
    int rr = b >> 2, qq = b & 3;
    for (int i = 0; i < 8; ++i) {
      int idx = qq * 2048 + i * 256 + t;   // (x,h)
      int x = idx >> 7, h = idx & 127;
      float val = w2[((size_t)x * RD + rr) * HD + h];
      __hip_bfloat16 hv = __float2bfloat16(val);
      w2t[((size_t)rr * XD + x) * HD + h] = *(u16*)&hv;
    }
  } else if (b < 384) {
    int bb = b - 256;
    int n = bb >> 4, sb = (bb & 15) * 64;
    for (int i = 0; i < 4; ++i) {
      int flat = i * 256 + t;
      int s = flat >> 4, ch = flat & 15;
      f32x4 d = *(const f32x4*)(r + ((size_t)(n * SITES + sb + s) * RD + ch * 4));
      *(f32x4*)&tl[s][ch * 4] = d;
    }
    __syncthreads();
    for (int i = 0; i < 4; ++i) {
      int flat = i * 256 + t;
      int rr = flat >> 4, ch = flat & 15;
      f32x4 o;
      o.x = tl[ch * 4 + 0][rr];
      o.y = tl[ch * 4 + 1][rr];
      o.z = tl[ch * 4 + 2][rr];
      o.w = tl[ch * 4 + 3][rr];
      *(f32x4*)(rt + ((size_t)(n * RD + rr) * SITES + sb + ch * 4)) = o;
    }
  } else {
    int f = (b - 384) * 256 + t;        // 524288 f32x4 units of ut
    int nh = f & 1, v = (f >> 1) & 63, uu = (f >> 7) & 63, rr = f >> 13;
    f32x4 o;
#pragma unroll
    for (int k = 0; k < 4; ++k)
      o[k] = u[(((size_t)(nh * 4 + k) * RD + rr) * UD + uu) * VD + v];
    *(f32x4*)(ut + (size_t)f * 4) = o;
  }
}

// ---------------- k_a: partial a over u-halves (R6 known-good, unchanged) -------
__global__ __launch_bounds__(256, 4) void k_a(const float* __restrict__ w1,
                                              const float* __restrict__ ut,
                                              float* __restrict__ part) {
  __shared__ float tile[32][34];      // h-local x v-local (+2 pad)
  int b = blockIdx.x;                 // 1024 = rr(64) x uh(2) x vh(2) x hb(4)
  int rr = b >> 4, uh = (b >> 3) & 1, vh = (b >> 2) & 1, hb = b & 3;
  int t = threadIdx.x;
  int vl = t >> 3, hs = t & 7;        // v-local (32), h-strip (4 h each)
  int v = vh * 32 + vl;
  int h0 = hb * 32 + hs * 4;
  const float* w1p = w1 + ((size_t)((rr * UD) + uh * 32) * VD + v) * HD + h0;
  const float* up  = ut + ((size_t)((rr * UD) + uh * 32) * VD + v) * NB;

  float acc[8][4];
#pragma unroll
  for (int n = 0; n < 8; ++n)
#pragma unroll
    for (int j = 0; j < 4; ++j) acc[n][j] = 0.f;

#pragma unroll 4
  for (int uu = 0; uu < 32; ++uu) {
    f32x4 wv = *(const f32x4*)(w1p + (size_t)uu * (VD * HD));
    f32x4 a0 = *(const f32x4*)(up + (size_t)uu * (VD * NB));
    f32x4 a1 = *(const f32x4*)(up + (size_t)uu * (VD * NB) + 4);
    float un[8];
    un[0] = a0.x; un[1] = a0.y; un[2] = a0.z; un[3] = a0.w;
    un[4] = a1.x; un[5] = a1.y; un[6] = a1.z; un[7] = a1.w;
#pragma unroll
    for (int n = 0; n < 8; ++n)
#pragma unroll
      for (int j = 0; j < 4; ++j) acc[n][j] += un[n] * wv[j];
  }

  // epilogue: LDS transpose per n -> f32x4 stores along v (full 128 B runs)
  int hl = t >> 3, vs = t & 7;
  float* pb = part + (size_t)uh * (NB * RD * HD * VD);
  for (int n = 0; n < 8; ++n) {
    __syncthreads();
#pragma unroll
    for (int j = 0; j < 4; ++j) tile[hs * 4 + j][vl] = acc[n][j];
    __syncthreads();
    f32x4 blk = *(const f32x4*)&tile[hl][vs * 4];
    *(f32x4*)(pb + ((size_t)(n * RD + rr) * HD + hb * 32 + hl) * VD + vh * 32 + vs * 4) = blk;
  }
}

// ---------------- k_a_red: at[n][r][h][v] bf16 = part[0] + part[1] (R6) ---------
__global__ __launch_bounds__(256) void k_a_red(const float* __restrict__ part,
                                               u16* __restrict__ at) {
  int i0 = blockIdx.x * 256 + threadIdx.x;   // 262144 threads, 4 f32x4 each
  const float* p1 = part + (size_t)NB * RD * HD * VD;
#pragma unroll
  for (int k = 0; k < 4; ++k) {
    size_t i = ((size_t)i0 + (size_t)k * 262144) * 4;
    f32x4 a = *(const f32x4*)(part + i);
    f32x4 c = *(const f32x4*)(p1 + i);
    u16x4 o;
#pragma unroll
    for (int j = 0; j < 4; ++j) {
      __hip_bfloat16 hv = __float2bfloat16(a[j] + c[j]);
      o[j] = *(u16*)&hv;
    }
    *(u16x4*)(at + i) = o;
  }
}

// ---------------- k_main: fused GEMM1 (P^T = A_r^T * V^T) + relu*r + GEMM2 ------
// R6 known-good structure (512 blocks x 256 thr, (256,1), 64 KB double-buffered
// swizzled Plds, ONE barrier per rr).  R10's single change: lds_barrier()
// instead of __syncthreads() -> no vmcnt(0) drain per rr; global prefetches
// survive the barrier.  WAR safety of dbuf+1-barrier proven in R6 (two barrier
// crossings separate read(k) from write(k+2)).
__global__ __launch_bounds__(256, 1) void k_main(const float* __restrict__ vin,
                                                 const u16* __restrict__ at,
                                                 const u16* __restrict__ w2t,
                                                 const float* __restrict__ rt,
                                                 float* __restrict__ pbuf) {
  __shared__ __align__(16) char Plds[2 * 128 * 256];   // 64 KB exactly
  int b = blockIdx.x;                 // 512 = n(8) x stile(8) x rchunk(8)
  int rc = b & 7, st = (b >> 3) & 7, n = b >> 6;
  int t = threadIdx.x;
  int w = t >> 6, L = t & 63, q = L >> 4, c = L & 15;
  int g2m = w >> 1, g2x = w & 1;      // GEMM2: s-half x x-half

  // V fragments (B-operand of GEMM1), register-resident for all r-steps
  bf16x8 vf[4][2];
#pragma unroll
  for (int nt = 0; nt < 4; ++nt)
#pragma unroll
    for (int ks = 0; ks < 2; ++ks) {
      int s = (w & 1) * 64 + nt * 16 + c;
      const float* vp = vin + ((size_t)(n * SITES + st * 128 + s) * VD + ks * 32 + q * 8);
      f32x4 a0 = *(const f32x4*)vp;
      f32x4 a1 = *(const f32x4*)(vp + 4);
      bf16x8 f;
      f[0] = (__bf16)a0.x; f[1] = (__bf16)a0.y; f[2] = (__bf16)a0.z; f[3] = (__bf16)a0.w;
      f[4] = (__bf16)a1.x; f[5] = (__bf16)a1.y; f[6] = (__bf16)a1.z; f[7] = (__bf16)a1.w;
      vf[nt][ks] = f;
    }

  f32x4 o[4][2];
#pragma unroll
  for (int i = 0; i < 4; i++)
#pragma unroll
    for (int j = 0; j < 2; j++) o[i][j] = (f32x4)0.f;

  int g1m = w >> 1, g1n = w & 1;      // GEMM1: h-half x s-half
  for (int rr = rc * 8; rr < rc * 8 + 8; ++rr) {
    const u16* abase = at + (size_t)(n * RD + rr) * 8192;   // [h][v] plain

    // A-frags direct from global: 16B = 8 consecutive v at fixed h
    bf16x8 af[4][2];
#pragma unroll
    for (int mt = 0; mt < 4; ++mt)
#pragma unroll
      for (int ks = 0; ks < 2; ++ks) {
        int h = g1m * 64 + mt * 16 + c;
        int vb = ks * 4 + q;
        af[mt][ks] = *(const bf16x8*)(abase + (size_t)h * VD + vb * 8);
      }
    // W2r b-frags from global (L2-hot)
    u32x4 wraw[2][4];
#pragma unroll
    for (int xt = 0; xt < 2; ++xt)
#pragma unroll
      for (int k2 = 0; k2 < 4; ++k2) {
        int xg = g2x * 32 + xt * 16 + c;
        wraw[xt][k2] = *(const u32x4*)((const char*)w2t +
                        (((size_t)(rr * XD + xg)) * HD + k2 * 32 + q * 8) * 2);
      }
    float rsc[4];
#pragma unroll
    for (int nt = 0; nt < 4; ++nt)
      rsc[nt] = rt[(size_t)(n * RD + rr) * SITES + st * 128 + g1n * 64 + nt * 16 + c];

    // GEMM1: D = A_r^T (m=h) x V^T (n=s), K=v=64
    f32x4 cc[4][4];
#pragma unroll
    for (int mt = 0; mt < 4; ++mt)
#pragma unroll
      for (int nt = 0; nt < 4; ++nt) cc[mt][nt] = (f32x4)0.f;
#pragma unroll
    for (int ks = 0; ks < 2; ++ks)
#pragma unroll
      for (int mt = 0; mt < 4; ++mt)
#pragma unroll
        for (int nt = 0; nt < 4; ++nt)
          cc[mt][nt] = __builtin_amdgcn_mfma_f32_16x16x32_bf16(af[mt][ks], vf[nt][ks],
                                                               cc[mt][nt], 0, 0, 0);

    // relu, scale by r, pack to Plds buf rr&1, XOR-swizzled 16B blocks:
    // element (s, h-block hb8=h>>3) stored at block (hb8 ^ (s&15)) within row s.
    char* PB = Plds + (rr & 1) * 32768;
#pragma unroll
    for (int mt = 0; mt < 4; ++mt)
#pragma unroll
      for (int nt = 0; nt < 4; ++nt) {
        float sc = rsc[nt];
        bf16x4 pv;
#pragma unroll
        for (int jj = 0; jj < 4; ++jj) {
          float x = cc[mt][nt][jj];
          x = x > 0.f ? x : 0.f;
          pv[jj] = (__bf16)(x * sc);
        }
        int s = g1n * 64 + nt * 16 + c;          // s&15 == c
        int blk = g1m * 8 + mt * 2 + (q >> 1);   // = h>>3
        *(bf16x4*)(PB + (size_t)s * 256 + (size_t)((blk ^ c) * 16 + (q & 1) * 8)) = pv;
      }
    lds_barrier();   // R10: lgkm-only barrier — no vmcnt(0) drain per rr

    // GEMM2: O[s,x] += P (m=s, A-op) x W2r^T (n=x), K=h=128
#pragma unroll
    for (int k2 = 0; k2 < 4; ++k2) {
      bf16x8 wf0 = __builtin_bit_cast(bf16x8, wraw[0][k2]);
      bf16x8 wf1 = __builtin_bit_cast(bf16x8, wraw[1][k2]);
#pragma unroll
      for (int mt = 0; mt < 4; ++mt) {
        int s = g2m * 64 + mt * 16 + c;          // s&15 == c
        int blk = k2 * 4 + q;                    // = h>>3
        bf16x8 pf = *(const bf16x8*)(PB + (size_t)s * 256 + (size_t)((blk ^ c) * 16));
        o[mt][0] = __builtin_amdgcn_mfma_f32_16x16x32_bf16(pf, wf0, o[mt][0], 0, 0, 0);
        o[mt][1] = __builtin_amdgcn_mfma_f32_16x16x32_bf16(pf, wf1, o[mt][1], 0, 0, 0);
      }
    }
  }
  // epilogue: plain vector stores to partial buffer pbuf[rc][n][st][x][s]
#pragma unroll
  for (int mt = 0; mt < 4; ++mt)
#pragma unroll
    for (int xt = 0; xt < 2; ++xt) {
      int s0 = g2m * 64 + mt * 16 + q * 4;
      int x = g2x * 32 + xt * 16 + c;
      size_t off = ((((size_t)rc * NB + n) * 8 + st) * XD + x) * 128 + s0;
      *(f32x4*)(pbuf + off) = o[mt][xt];
    }
}

// ---------------- k_reduce: out[n][s][x] = sum_rc pbuf[rc][n][st][x][s] (R6) ----
__global__ __launch_bounds__(256) void k_reduce(const float* __restrict__ pbuf,
                                                float* __restrict__ out) {
  __shared__ float tile[128][17];
  int b = blockIdx.x;                 // 256 = n(8) x st(8) x xq(4)
  int n = b >> 5, st = (b >> 2) & 7, xq = b & 3;
  int t = threadIdx.x;
  int sq = t & 31, xl = t >> 5;       // phase-1: s-quad, x-lane (8)
#pragma unroll
  for (int p = 0; p < 2; ++p) {
    int x = xq * 16 + p * 8 + xl;
    f32x4 sum = (f32x4)0.f;
#pragma unroll
    for (int rcc = 0; rcc < 8; ++rcc) {
      size_t off = ((((size_t)rcc * NB + n) * 8 + st) * XD + x) * 128 + sq * 4;
      f32x4 d = *(const f32x4*)(pbuf + off);
      sum.x += d.x; sum.y += d.y; sum.z += d.z; sum.w += d.w;
    }
#pragma unroll
    for (int k = 0; k < 4; ++k) tile[sq * 4 + k][p * 8 + xl] = sum[k];
  }
  __syncthreads();
  // phase-2: coalesced out write, f32x4 along x
#pragma unroll
  for (int k = 0; k < 2; ++k) {
    int flat = k * 256 + t;
    int s = flat >> 2, c4 = flat & 3;
    f32x4 o;
#pragma unroll
    for (int j = 0; j < 4; ++j) o[j] = tile[s][c4 * 4 + j];
    *(f32x4*)(out + ((size_t)(n * SITES + st * 128 + s) * XD + xq * 16 + c4 * 4)) = o;
  }
}

extern "C" void kernel_launch(void* const* d_in, const int* in_sizes, int n_in,
                              void* d_out, int out_size, void* d_ws, size_t ws_size,
                              hipStream_t stream) {
  const float* r  = (const float*)d_in[0];
  const float* u  = (const float*)d_in[1];
  const float* v  = (const float*)d_in[2];
  const float* w1 = (const float*)d_in[3];
  const float* w2 = (const float*)d_in[4];
  float* out = (float*)d_out;
  char* ws = (char*)d_ws;
  u16* at     = (u16*)(ws);                         // 8 MB  bf16 a, [n][r][h][v]
  u16* w2t    = (u16*)(ws + ((size_t)8 << 20));     // 1 MB  bf16 w2 [r][x][h]
  float* rt   = (float*)(ws + ((size_t)9 << 20));   // 2 MB  fp32 r [n][r][s]
  float* ut   = (float*)(ws + ((size_t)11 << 20));  // 8 MB  fp32 u [r][u][v][n]
  float* part = (float*)(ws + ((size_t)19 << 20));  // 32 MB fp32 a-partials [uh][n][r][h][v]
  float* pbuf = (float*)(ws + ((size_t)51 << 20));  // 16 MB fp32 out-partials [rc][n][st][x][s]

  hipLaunchKernelGGL(kprep, dim3(2432), dim3(256), 0, stream, w2, w2t, r, rt, u, ut);
  hipLaunchKernelGGL(k_a, dim3(1024), dim3(256), 0, stream, w1, ut, part);
  hipLaunchKernelGGL(k_a_red, dim3(1024), dim3(256), 0, stream, part, at);
  hipLaunchKernelGGL(k_main, dim3(512), dim3(256), 0, stream, v, at, w2t, rt, pbuf);
  hipLaunchKernelGGL(k_reduce, dim3(256), dim3(256), 0, stream, pbuf, out);
}